// Round 1
// baseline (907.450 us; speedup 1.0000x reference)
//
#include <hip/hip_runtime.h>
#include <stdint.h>

#define D_DIM 12544
#define NROIS 8192
#define NCOLS 168        // valid output cols: 32+124+3+7+2
#define NCPAD 176        // padded cols in Wp (cols 168..175 are zeros)
#define NT 11
#define SPLIT 8
#define KSPLIT (D_DIM / SPLIT)   // 1568
#define BK 32
#define KITERS (KSPLIT / BK)     // 49
#define BM 64
#define NRB (NROIS / BM)         // 128 row-blocks

// LDS: W tile only. 192 cols x 32 bf16 (64B) padded to 80B -> 2-way banks max.
#define WCOL_B 80
#define WL_COLS 192
#define WBUF_BYTES (WL_COLS * WCOL_B)   // 15360; x2 dbuf = 30720 B -> 4+ blocks/CU

typedef __attribute__((ext_vector_type(8))) short short8;   // 8 bf16 (MFMA A/B frag)
typedef __attribute__((ext_vector_type(4))) float floatx4;  // MFMA C/D frag

__device__ __forceinline__ uint32_t pk_bf16(float a, float b) {
    uint32_t ua = __float_as_uint(a);
    uint32_t ub = __float_as_uint(b);
    ua = (ua + 0x7FFFu + ((ua >> 16) & 1u)) >> 16;
    ub = (ub + 0x7FFFu + ((ub >> 16) & 1u)) >> 16;
    return ua | (ub << 16);
}

// ---------------- pack W (5 heads) -> Wp[NCPAD][D_DIM] bf16, K-major --------
// Also zeroes the per-row-block tickets used by the fused reduction.
__global__ __launch_bounds__(256) void pack_w(
        const float* __restrict__ Wc, const float* __restrict__ Wr,
        const float* __restrict__ Wf, const float* __restrict__ Wco,
        const float* __restrict__ Wm, uint16_t* __restrict__ Wp,
        uint32_t* __restrict__ tickets) {
    __shared__ float tile[64][33];
    int k0 = blockIdx.x * 64;
    int c0 = blockIdx.y * 32;
    int t  = threadIdx.x;

    if (blockIdx.x == 0 && blockIdx.y == 0 && t < NRB) tickets[t] = 0;

    int rc = t & 31;        // read col within tile
    int rk = t >> 5;        // 0..7
#pragma unroll
    for (int rr = 0; rr < 8; ++rr) {
        int k = rr * 8 + rk;
        int kk = k0 + k;
        int c = c0 + rc;
        float v = 0.f;
        if (c < 32)       v = Wc[(size_t)kk * 32  + c];
        else if (c < 156) v = Wr[(size_t)kk * 124 + (c - 32)];
        else if (c < 159) v = Wf[(size_t)kk * 3   + (c - 156)];
        else if (c < 166) v = Wco[(size_t)kk * 7  + (c - 159)];
        else if (c < 168) v = Wm[(size_t)kk * 2   + (c - 166)];
        tile[k][rc] = v;
    }
    __syncthreads();

    int wc = t >> 3;        // 0..31 write col
    int wk = t & 7;         // k-chunk (8 bf16 = 16 B)
    int c  = c0 + wc;
    if (c < NCPAD) {
        uint32_t o[4];
#pragma unroll
        for (int j = 0; j < 4; ++j)
            o[j] = pk_bf16(tile[wk * 8 + 2 * j][wc], tile[wk * 8 + 2 * j + 1][wc]);
        uint4 v = make_uint4(o[0], o[1], o[2], o[3]);
        *(uint4*)(Wp + (size_t)c * D_DIM + k0 + wk * 8) = v;
    }
}

// ---------------- split-K GEMM + fused ticket reduction ---------------------
// X fragments load DIRECTLY from global (each X element feeds exactly one
// lane's MFMA frag; per-wave pattern is 16 rows x 128 B contiguous — identical
// coalescing to LDS staging, so the LDS round-trip was pure overhead).
// W double-buffered in LDS, one barrier per K-iter. 8th split-block of each
// row-block reduces bf16 partials + bias and scatters to the 5 heads.
__global__ __launch_bounds__(256) void gemm_fused(
        const float* __restrict__ X, const uint16_t* __restrict__ Wp,
        uint16_t* __restrict__ parts, uint32_t* __restrict__ tickets,
        const float* __restrict__ bc, const float* __restrict__ br,
        const float* __restrict__ bfa, const float* __restrict__ bco,
        const float* __restrict__ bm, float* __restrict__ out) {
    __shared__ __attribute__((aligned(16))) char lds[2 * WBUF_BYTES];
    __shared__ uint32_t s_ticket;

    int b     = blockIdx.x;       // 0..1023
    int split = b & 7;            // one split per XCD (round-robin): W slice 552 KB L2-resident
    int rb    = b >> 3;           // 0..127
    int row0  = rb * BM;
    int kbase = split * KSPLIT;

    int t    = threadIdx.x;
    int wave = t >> 6;
    int lane = t & 63;
    int n    = lane & 15;         // X row within wave tile / D col
    int quad = lane >> 4;         // k-chunk / D row group

    // ---- W staging roles (cooperative, 192 cols x 64 B per iter) ----
    int sw_col = t >> 2;          // 0..63, rounds add 64/128
    int sw_ch  = t & 3;           // 16B chunk within col's 64B k-row
    int c0g = sw_col       < NCPAD ? sw_col       : NCPAD - 1;
    int c1g = sw_col + 64  < NCPAD ? sw_col + 64  : NCPAD - 1;
    int c2g = sw_col + 128 < NCPAD ? sw_col + 128 : NCPAD - 1;
    const uint16_t* wg0 = Wp + (size_t)c0g * D_DIM + kbase + sw_ch * 8;
    const uint16_t* wg1 = Wp + (size_t)c1g * D_DIM + kbase + sw_ch * 8;
    const uint16_t* wg2 = Wp + (size_t)c2g * D_DIM + kbase + sw_ch * 8;
    int w_st0 = (sw_col)       * WCOL_B + sw_ch * 16;
    int w_st1 = (sw_col + 64)  * WCOL_B + sw_ch * 16;
    int w_st2 = (sw_col + 128) * WCOL_B + sw_ch * 16;

    // ---- X fragment pointer: this lane's own 8 fp32 per iter ----
    const float* xg = X + (size_t)(row0 + wave * 16 + n) * D_DIM + kbase + quad * 8;

    int wf_off = n * WCOL_B + quad * 16;   // + tt*16*WCOL_B

    floatx4 acc[NT];
#pragma unroll
    for (int tt = 0; tt < NT; ++tt) acc[tt] = (floatx4)0.f;

    // ---- prologue: iter-0 X frag to regs, W tile to buf0 ----
    float4 px0 = *(const float4*)xg;
    float4 px1 = *(const float4*)(xg + 4);
    xg += BK;
    {
        short8 pw0 = *(const short8*)wg0; wg0 += BK;
        short8 pw1 = *(const short8*)wg1; wg1 += BK;
        short8 pw2 = *(const short8*)wg2; wg2 += BK;
        *(short8*)(lds + w_st0) = pw0;
        *(short8*)(lds + w_st1) = pw1;
        *(short8*)(lds + w_st2) = pw2;
    }
    int cur = 0;

    for (int it = 0; it < KITERS; ++it) {
        __syncthreads();   // buf[cur] staged; prev iter's readers of buf[cur^1] done

        // issue next-iter global loads (in flight during convert+MFMA phase)
        float4 nx0, nx1; short8 nw0, nw1, nw2;
        bool more = (it + 1 < KITERS);
        if (more) {
            nx0 = *(const float4*)xg;
            nx1 = *(const float4*)(xg + 4);
            xg += BK;
            nw0 = *(const short8*)wg0; wg0 += BK;
            nw1 = *(const short8*)wg1; wg1 += BK;
            nw2 = *(const short8*)wg2; wg2 += BK;
        }

        // convert this iter's X frag fp32 -> bf16
        union { uint32_t u[4]; short8 s; } xp;
        xp.u[0] = pk_bf16(px0.x, px0.y); xp.u[1] = pk_bf16(px0.z, px0.w);
        xp.u[2] = pk_bf16(px1.x, px1.y); xp.u[3] = pk_bf16(px1.z, px1.w);
        short8 xf = xp.s;

        const char* cb = lds + cur * WBUF_BYTES;
#pragma unroll
        for (int tt = 0; tt < NT; ++tt) {
            short8 wf = *(const short8*)(cb + wf_off + tt * (16 * WCOL_B));
            acc[tt] = __builtin_amdgcn_mfma_f32_16x16x32_bf16(wf, xf, acc[tt], 0, 0, 0);
        }

        // stage next W tile into other buffer (its readers finished before the
        // barrier at top of this iter — single barrier per iter suffices)
        if (more) {
            char* nb = lds + (cur ^ 1) * WBUF_BYTES;
            *(short8*)(nb + w_st0) = nw0;
            *(short8*)(nb + w_st1) = nw1;
            *(short8*)(nb + w_st2) = nw2;
            px0 = nx0; px1 = nx1;
            cur ^= 1;
        }
    }

    // ---- write bf16 partials: D layout col(n)=X row, out-col = quad*4+reg (+16*tt)
    uint16_t* pb = parts + ((size_t)split * NROIS + row0 + wave * 16 + n) * NCOLS;
#pragma unroll
    for (int tt = 0; tt < NT; ++tt) {
        int col0 = tt * 16 + quad * 4;
        if (col0 + 3 < NCOLS) {
            uint32_t lo = pk_bf16(acc[tt].x, acc[tt].y);
            uint32_t hi = pk_bf16(acc[tt].z, acc[tt].w);
            uint2 v = make_uint2(lo, hi);
            *(uint2*)(pb + col0) = v;
        }
    }

    // ---- ticket: 8th arriver for this row-block reduces + biases + scatters
    __threadfence();                          // release: flush partials (device scope)
    if (t == 0) s_ticket = atomicAdd(&tickets[rb], 1u);
    __syncthreads();
    if (s_ticket != SPLIT - 1) return;
    __threadfence();                          // acquire: see other XCDs' partials

    const size_t PS = (size_t)NROIS * NCOLS;
    for (int idx = t; idx < BM * NCOLS; idx += 256) {
        int r = idx / NCOLS;                  // const div -> magic mul
        int c = idx - r * NCOLS;
        size_t off = (size_t)(row0 + r) * NCOLS + c;
        float v = 0.f;
#pragma unroll
        for (int s = 0; s < SPLIT; ++s)
            v += __uint_as_float((uint32_t)parts[off + (size_t)s * PS] << 16);
        float bias; size_t oidx;
        size_t rr = (size_t)(row0 + r);
        if (c < 32)       { bias = bc[c];        oidx = rr * 32  + c; }
        else if (c < 156) { bias = br[c - 32];   oidx = 262144u  + rr * 124 + (c - 32); }
        else if (c < 159) { bias = bfa[c - 156]; oidx = 1277952u + rr * 3   + (c - 156); }
        else if (c < 166) { bias = bco[c - 159]; oidx = 1302528u + rr * 7   + (c - 159); }
        else              { bias = bm[c - 166];  oidx = 1359872u + rr * 2   + (c - 166); }
        out[oidx] = v + bias;
    }
}

extern "C" void kernel_launch(void* const* d_in, const int* in_sizes, int n_in,
                              void* d_out, int out_size, void* d_ws, size_t ws_size,
                              hipStream_t stream) {
    const float* X   = (const float*)d_in[0];
    const float* Wc  = (const float*)d_in[1];
    const float* bc  = (const float*)d_in[2];
    const float* Wr  = (const float*)d_in[3];
    const float* br  = (const float*)d_in[4];
    const float* Wf  = (const float*)d_in[5];
    const float* bfa = (const float*)d_in[6];
    const float* Wco = (const float*)d_in[7];
    const float* bco = (const float*)d_in[8];
    const float* Wm  = (const float*)d_in[9];
    const float* bm  = (const float*)d_in[10];

    uint16_t* Wp    = (uint16_t*)d_ws;                                    // 4,415,488 B
    uint16_t* parts = (uint16_t*)((char*)d_ws + (size_t)NCPAD * D_DIM * 2); // 22,020,096 B
    uint32_t* tickets = (uint32_t*)((char*)d_ws + (size_t)NCPAD * D_DIM * 2
                                    + (size_t)SPLIT * NROIS * NCOLS * 2);   // 512 B
    float* out = (float*)d_out;

    pack_w<<<dim3(D_DIM / 64, 6), 256, 0, stream>>>(Wc, Wr, Wf, Wco, Wm, Wp, tickets);
    gemm_fused<<<SPLIT * NRB, 256, 0, stream>>>(X, Wp, parts, tickets,
                                                bc, br, bfa, bco, bm, out);
}

// Round 2
// 610.191 us; speedup vs baseline: 1.4872x; 1.4872x over previous
//
#include <hip/hip_runtime.h>
#include <stdint.h>

#define D_DIM 12544
#define NROIS 8192
#define NCOLS 168        // valid output cols: 32+124+3+7+2
#define NCPAD 176        // padded cols in Wp (cols 168..175 are zeros)
#define NT 11
#define SPLIT 8
#define KSPLIT (D_DIM / SPLIT)   // 1568
#define BK 32
#define KITERS (KSPLIT / BK)     // 49
#define BM 64

// LDS: W tile only. 192 cols x 32 bf16 (64B) padded to 80B -> 2-way banks max.
#define WCOL_B 80
#define WL_COLS 192
#define WBUF_BYTES (WL_COLS * WCOL_B)   // 15360; x2 dbuf = 30720 B

typedef __attribute__((ext_vector_type(8))) short short8;   // 8 bf16 (MFMA A/B frag)
typedef __attribute__((ext_vector_type(4))) float floatx4;  // MFMA C/D frag

__device__ __forceinline__ uint32_t pk_bf16(float a, float b) {
    uint32_t ua = __float_as_uint(a);
    uint32_t ub = __float_as_uint(b);
    ua = (ua + 0x7FFFu + ((ua >> 16) & 1u)) >> 16;
    ub = (ub + 0x7FFFu + ((ub >> 16) & 1u)) >> 16;
    return ua | (ub << 16);
}

// ---------------- pack W (5 heads) -> Wp[NCPAD][D_DIM] bf16, K-major --------
__global__ __launch_bounds__(256) void pack_w(
        const float* __restrict__ Wc, const float* __restrict__ Wr,
        const float* __restrict__ Wf, const float* __restrict__ Wco,
        const float* __restrict__ Wm, uint16_t* __restrict__ Wp) {
    __shared__ float tile[64][33];
    int k0 = blockIdx.x * 64;
    int c0 = blockIdx.y * 32;
    int t  = threadIdx.x;

    int rc = t & 31;        // read col within tile
    int rk = t >> 5;        // 0..7
#pragma unroll
    for (int rr = 0; rr < 8; ++rr) {
        int k = rr * 8 + rk;
        int kk = k0 + k;
        int c = c0 + rc;
        float v = 0.f;
        if (c < 32)       v = Wc[(size_t)kk * 32  + c];
        else if (c < 156) v = Wr[(size_t)kk * 124 + (c - 32)];
        else if (c < 159) v = Wf[(size_t)kk * 3   + (c - 156)];
        else if (c < 166) v = Wco[(size_t)kk * 7  + (c - 159)];
        else if (c < 168) v = Wm[(size_t)kk * 2   + (c - 166)];
        tile[k][rc] = v;
    }
    __syncthreads();

    int wc = t >> 3;        // 0..31 write col
    int wk = t & 7;         // k-chunk (8 bf16 = 16 B)
    int c  = c0 + wc;
    if (c < NCPAD) {
        uint32_t o[4];
#pragma unroll
        for (int j = 0; j < 4; ++j)
            o[j] = pk_bf16(tile[wk * 8 + 2 * j][wc], tile[wk * 8 + 2 * j + 1][wc]);
        uint4 v = make_uint4(o[0], o[1], o[2], o[3]);
        *(uint4*)(Wp + (size_t)c * D_DIM + k0 + wk * 8) = v;
    }
}

// ---------------- split-K GEMM, W LDS-staged, X direct, parts bf16 ----------
// X fragments load DIRECTLY from global: each X element feeds exactly one
// lane's MFMA fragment; the per-wave pattern (16 rows x 128 B contiguous) has
// identical coalescing to cooperative LDS staging, so the LDS round-trip for X
// was pure overhead. W double-buffered in LDS, one barrier per K-iter.
// NO cross-block fences/tickets: round-1 showed agent-scope __threadfence()
// (L2 writeback per XCD) costs ~460 us of L2 thrash -- keep the kernel-boundary
// as the release/acquire point and reduce in a separate tiny kernel.
__global__ __launch_bounds__(256) void gemm_split(const float* __restrict__ X,
                                                  const uint16_t* __restrict__ Wp,
                                                  uint16_t* __restrict__ parts) {
    __shared__ __attribute__((aligned(16))) char lds[2 * WBUF_BYTES];

    int b     = blockIdx.x;       // 0..1023
    int split = b & 7;            // one split per XCD (round-robin): W slice L2-resident
    int rb    = b >> 3;           // 0..127
    int row0  = rb * BM;
    int kbase = split * KSPLIT;

    int t    = threadIdx.x;
    int wave = t >> 6;
    int lane = t & 63;
    int n    = lane & 15;         // X row within wave tile / D col
    int quad = lane >> 4;         // k-chunk / D row group

    // ---- W staging roles (cooperative, 192 cols x 64 B per iter) ----
    int sw_col = t >> 2;          // 0..63, rounds add 64/128
    int sw_ch  = t & 3;           // 16B chunk within col's 64B k-row
    int c0g = sw_col       < NCPAD ? sw_col       : NCPAD - 1;
    int c1g = sw_col + 64  < NCPAD ? sw_col + 64  : NCPAD - 1;
    int c2g = sw_col + 128 < NCPAD ? sw_col + 128 : NCPAD - 1;
    const uint16_t* wg0 = Wp + (size_t)c0g * D_DIM + kbase + sw_ch * 8;
    const uint16_t* wg1 = Wp + (size_t)c1g * D_DIM + kbase + sw_ch * 8;
    const uint16_t* wg2 = Wp + (size_t)c2g * D_DIM + kbase + sw_ch * 8;
    int w_st0 = (sw_col)       * WCOL_B + sw_ch * 16;
    int w_st1 = (sw_col + 64)  * WCOL_B + sw_ch * 16;
    int w_st2 = (sw_col + 128) * WCOL_B + sw_ch * 16;

    // ---- X fragment pointer: this lane's own 8 fp32 per iter ----
    const float* xg = X + (size_t)(row0 + wave * 16 + n) * D_DIM + kbase + quad * 8;

    int wf_off = n * WCOL_B + quad * 16;   // + tt*16*WCOL_B

    floatx4 acc[NT];
#pragma unroll
    for (int tt = 0; tt < NT; ++tt) acc[tt] = (floatx4)0.f;

    // ---- prologue: iter-0 X frag to regs, W tile to buf0 ----
    float4 px0 = *(const float4*)xg;
    float4 px1 = *(const float4*)(xg + 4);
    xg += BK;
    {
        short8 pw0 = *(const short8*)wg0; wg0 += BK;
        short8 pw1 = *(const short8*)wg1; wg1 += BK;
        short8 pw2 = *(const short8*)wg2; wg2 += BK;
        *(short8*)(lds + w_st0) = pw0;
        *(short8*)(lds + w_st1) = pw1;
        *(short8*)(lds + w_st2) = pw2;
    }
    int cur = 0;

    for (int it = 0; it < KITERS; ++it) {
        __syncthreads();   // buf[cur] staged; prev iter's readers of buf[cur^1] done

        // issue next-iter global loads (in flight during convert+MFMA phase)
        float4 nx0, nx1; short8 nw0, nw1, nw2;
        bool more = (it + 1 < KITERS);
        if (more) {
            nx0 = *(const float4*)xg;
            nx1 = *(const float4*)(xg + 4);
            xg += BK;
            nw0 = *(const short8*)wg0; wg0 += BK;
            nw1 = *(const short8*)wg1; wg1 += BK;
            nw2 = *(const short8*)wg2; wg2 += BK;
        }

        // convert this iter's X frag fp32 -> bf16 (registers, no LDS round-trip)
        union { uint32_t u[4]; short8 s; } xp;
        xp.u[0] = pk_bf16(px0.x, px0.y); xp.u[1] = pk_bf16(px0.z, px0.w);
        xp.u[2] = pk_bf16(px1.x, px1.y); xp.u[3] = pk_bf16(px1.z, px1.w);
        short8 xf = xp.s;

        const char* cb = lds + cur * WBUF_BYTES;
#pragma unroll
        for (int tt = 0; tt < NT; ++tt) {
            short8 wf = *(const short8*)(cb + wf_off + tt * (16 * WCOL_B));
            acc[tt] = __builtin_amdgcn_mfma_f32_16x16x32_bf16(wf, xf, acc[tt], 0, 0, 0);
        }

        // stage next W tile into other buffer (its readers finished before the
        // barrier at top of this iter -- single barrier per iter suffices)
        if (more) {
            char* nb = lds + (cur ^ 1) * WBUF_BYTES;
            *(short8*)(nb + w_st0) = nw0;
            *(short8*)(nb + w_st1) = nw1;
            *(short8*)(nb + w_st2) = nw2;
            px0 = nx0; px1 = nx1;
            cur ^= 1;
        }
    }

    // ---- epilogue: D layout col(n)=X row, out-col = quad*4+reg (+16*tt) ----
    uint16_t* pb = parts + ((size_t)split * NROIS + row0 + wave * 16 + n) * NCOLS;
#pragma unroll
    for (int tt = 0; tt < NT; ++tt) {
        int col0 = tt * 16 + quad * 4;
        if (col0 + 3 < NCOLS) {
            uint32_t lo = pk_bf16(acc[tt].x, acc[tt].y);
            uint32_t hi = pk_bf16(acc[tt].z, acc[tt].w);
            uint2 v = make_uint2(lo, hi);
            *(uint2*)(pb + col0) = v;
        }
    }
}

// ---------------- reduce partials (bf16) + bias, scatter to 5 heads ---------
__global__ void reduce_out(const uint16_t* __restrict__ parts,
                           const float* __restrict__ bc, const float* __restrict__ br,
                           const float* __restrict__ bf, const float* __restrict__ bco,
                           const float* __restrict__ bm, float* __restrict__ out) {
    int r = blockIdx.x;
    int c = threadIdx.x;
    if (c >= NCOLS) return;
    const size_t S = (size_t)NROIS * NCOLS;
    size_t off = (size_t)r * NCOLS + c;
    float v = 0.f;
#pragma unroll
    for (int s = 0; s < SPLIT; ++s)
        v += __uint_as_float((uint32_t)parts[off + (size_t)s * S] << 16);
    float bias; size_t oidx;
    if (c < 32)       { bias = bc[c];        oidx = (size_t)r * 32  + c; }
    else if (c < 156) { bias = br[c - 32];   oidx = 262144u  + (size_t)r * 124 + (c - 32); }
    else if (c < 159) { bias = bf[c - 156];  oidx = 1277952u + (size_t)r * 3   + (c - 156); }
    else if (c < 166) { bias = bco[c - 159]; oidx = 1302528u + (size_t)r * 7   + (c - 159); }
    else              { bias = bm[c - 166];  oidx = 1359872u + (size_t)r * 2   + (c - 166); }
    out[oidx] = v + bias;
}

extern "C" void kernel_launch(void* const* d_in, const int* in_sizes, int n_in,
                              void* d_out, int out_size, void* d_ws, size_t ws_size,
                              hipStream_t stream) {
    const float* X   = (const float*)d_in[0];
    const float* Wc  = (const float*)d_in[1];
    const float* bc  = (const float*)d_in[2];
    const float* Wr  = (const float*)d_in[3];
    const float* br  = (const float*)d_in[4];
    const float* Wf  = (const float*)d_in[5];
    const float* bfa = (const float*)d_in[6];
    const float* Wco = (const float*)d_in[7];
    const float* bco = (const float*)d_in[8];
    const float* Wm  = (const float*)d_in[9];
    const float* bm  = (const float*)d_in[10];

    uint16_t* Wp    = (uint16_t*)d_ws;                                      // 4,415,488 B
    uint16_t* parts = (uint16_t*)((char*)d_ws + (size_t)NCPAD * D_DIM * 2); // 22,020,096 B

    float* out = (float*)d_out;

    pack_w<<<dim3(D_DIM / 64, 6), 256, 0, stream>>>(Wc, Wr, Wf, Wco, Wm, Wp);
    gemm_split<<<1024, 256, 0, stream>>>(X, Wp, parts);
    reduce_out<<<NROIS, 192, 0, stream>>>(parts, bc, br, bfa, bco, bm, out);
}